// Round 8
// baseline (366.609 us; speedup 1.0000x reference)
//
#include <hip/hip_runtime.h>
#include <cstdint>

#define NB 8
#define TS 2048
#define NE 1024
#define HD 64
#define MTOT (NB*TS)
#define NBLK 256

typedef float     f4  __attribute__((ext_vector_type(4)));
typedef short     s8v __attribute__((ext_vector_type(8)));
typedef int       i4v __attribute__((ext_vector_type(4)));
typedef _Float16  h8  __attribute__((ext_vector_type(8)));

__device__ __forceinline__ short f2bf(float f) {  // RNE
  union { float f; uint32_t u; } x; x.f = f;
  return (short)((x.u + 0x7FFFu + ((x.u >> 16) & 1u)) >> 16);
}

// pack two fp32 -> (bf16(lo) | bf16(hi)<<16) via +0x8000 round + v_perm byte select
__device__ __forceinline__ int pack2(float lo, float hi) {
  union { float f; uint32_t u; } a, b; a.f = lo; b.f = hi;
  return (int)__builtin_amdgcn_perm(b.u + 0x8000u, a.u + 0x8000u, 0x07060302u);
}

// async global->LDS DMA, 16B/lane; lptr wave-uniform, lane i -> lptr + i*16
__device__ __forceinline__ void gl2lds(const void* gptr, void* lptr) {
  auto g = (const __attribute__((address_space(1))) uint32_t*)gptr;
  auto l = (__attribute__((address_space(3))) uint32_t*)lptr;
  __builtin_amdgcn_global_load_lds(g, l, 16, 0, 0);
}

// block barrier keeping the N newest vmem ops in flight
template <int N>
__device__ __forceinline__ void wait_barrier() {
  asm volatile("s_waitcnt vmcnt(%0) lgkmcnt(0)" :: "n"(N) : "memory");
  __builtin_amdgcn_s_barrier();
}

// grid barrier: device-scope release/acquire (per-XCD L2 writeback/invalidate via threadfence)
__device__ __forceinline__ void gridbar(uint32_t* cnt, int id) {
  __threadfence();
  __syncthreads();
  if (threadIdx.x == 0) {
    __hip_atomic_fetch_add(&cnt[id], 1u, __ATOMIC_RELEASE, __HIP_MEMORY_SCOPE_AGENT);
    while (__hip_atomic_load(&cnt[id], __ATOMIC_ACQUIRE, __HIP_MEMORY_SCOPE_AGENT) < NBLK)
      __builtin_amdgcn_s_sleep(8);
  }
  __syncthreads();
  __threadfence();
}

// ONE dispatch: phase0 wconv -> gridbar -> phase1 proj -> gridbar -> phase2 attn.
// grid 256 (=CU count), 512 thr, LDS 96 KB (forces 1 block/CU -> all blocks co-resident).
__global__ __launch_bounds__(512, 2) void fused_kernel(
    const float* __restrict__ x, const float* __restrict__ Wk,
    const float* __restrict__ Wq, const float* __restrict__ Wv,
    short* __restrict__ wb, short* __restrict__ qo, short* __restrict__ ko,
    _Float16* __restrict__ vo, float* __restrict__ out, uint32_t* cnt)
{
  __shared__ __align__(16) char smem[98304];
  const int tid = threadIdx.x;
  const int wv = tid >> 6, lane = tid & 63, n = lane & 15, quad = lane >> 4;
  const int blk = blockIdx.x;
  const f4 fz = {0.f, 0.f, 0.f, 0.f};

  // ===== phase 0: W fp32 -> bf16 (q-scale folded). wb [192][1024]: q|k|v =====
  if (blk < 192) {
    const int idx = blk * 1024 + tid * 2;
    const int p = idx >> 16;
    const int off = idx & 65535;
    const float* W = (p == 0) ? Wq : (p == 1) ? Wk : Wv;
    const float s = (p == 0) ? 0.18033688011112042f : 1.0f; // (1/8)*log2(e)
    const float2 v = *(const float2*)&W[off];
    *(int*)&wb[idx] = pack2(v.x * s, v.y * s);
  }
  gridbar(cnt, 0);

  // ===== phase 1: proj. 64 rows/block in two 32-row passes, continuous 32-iter pipeline.
  // Xs 4-buf fp32 (32 KB), Ws 2-buf bf16 (48 KB). Wave = 16 rows x 48 cols (mg 2 x cg 4).
  {
    float (*Xs)[32][64] = (float (*)[32][64])smem;
    short (*Ws)[192][64] = (short (*)[192][64])(smem + 32768);
    const int r0 = blk * 64;
    const int mg = wv & 1, cg = wv >> 1;

    auto dmaX = [&](int t) {          // chunk t: rows r0+(t>>4)*32, K-cols (t&15)*64, buf t&3
      const int rb = r0 + ((t >> 4) << 5);
      const int c = (t & 15) << 6;
      const int r = (wv << 2) + (lane >> 4);
      const int s = lane & 15;
      gl2lds(&x[(size_t)(rb + r) * NE + c + (((s + r) & 15) << 2)], &Xs[t & 3][wv << 2][0]);
    };
    auto dmaW = [&](int t) {          // chunk (t&15), buf t&1
      const int c = (t & 15) << 6;
#pragma unroll
      for (int u = 0; u < 3; ++u) {
        const int C0 = (wv * 3 + u) * 8;
        const int col = C0 + (lane >> 3);
        const int s = lane & 7;
        gl2lds(&wb[(size_t)col * NE + c + (((s + col) & 7) << 3)], &Ws[t & 1][C0][0]);
      }
    };

    f4 acc[2][3];
#pragma unroll
    for (int h = 0; h < 2; ++h)
#pragma unroll
      for (int nf = 0; nf < 3; ++nf) acc[h][nf] = fz;

    dmaW(0); dmaX(0); dmaX(1); dmaX(2);
    wait_barrier<2>();                // X0,W0 landed; X1,X2 flying

    for (int t = 0; t < 32; ++t) {
      if (t < 31) dmaW(t + 1);
      if (t < 29) dmaX(t + 3);
      {
        const int bx = t & 3, bw = t & 1;
        const int row = (mg << 4) + n;
        s8v a[2];
#pragma unroll
        for (int kc = 0; kc < 2; ++kc) {
          const int u0 = kc * 8 + quad * 2;
          const float* pr = &Xs[bx][row][0];
          const f4 f0 = *(const f4*)(pr + (((u0    ) - row) & 15) * 4);
          const f4 f1 = *(const f4*)(pr + (((u0 + 1) - row) & 15) * 4);
          i4v ai;
          ai[0] = pack2(f0[0], f0[1]); ai[1] = pack2(f0[2], f0[3]);
          ai[2] = pack2(f1[0], f1[1]); ai[3] = pack2(f1[2], f1[3]);
          a[kc] = __builtin_bit_cast(s8v, ai);
        }
        f4* ac = acc[t >> 4];
#pragma unroll
        for (int nf = 0; nf < 3; ++nf) {
          const int col = cg * 48 + nf * 16 + n;
          const s8v b0 = *(const s8v*)&Ws[bw][col][(((    quad) - col) & 7) * 8];
          const s8v b1 = *(const s8v*)&Ws[bw][col][(((4 + quad) - col) & 7) * 8];
          ac[nf] = __builtin_amdgcn_mfma_f32_16x16x32_bf16(a[0], b0, ac[nf], 0, 0, 0);
          ac[nf] = __builtin_amdgcn_mfma_f32_16x16x32_bf16(a[1], b1, ac[nf], 0, 0, 0);
        }
      }
      if (t < 29)      wait_barrier<1>();   // keep X(t+3) flying
      else if (t < 31) wait_barrier<0>();
    }

    // epilogue
#pragma unroll
    for (int h = 0; h < 2; ++h)
#pragma unroll
      for (int nf = 0; nf < 3; ++nf) {
        const int base = cg * 48 + nf * 16;
        const int p = base >> 6;
        const int rcol = (base & 63) + n;
#pragma unroll
        for (int i = 0; i < 4; ++i) {
          const int R = r0 + h * 32 + mg * 16 + quad * 4 + i;
          const float av = acc[h][nf][i];
          if (p == 0)      qo[(size_t)R * HD + rcol] = f2bf(av);
          else if (p == 1) ko[(size_t)R * HD + rcol] = f2bf(av);
          else {
            // V transposed [b][d][t'], 32-key-group swizzle: pos = quad*8 + f*4 + i
            const int t2 = R & (TS - 1), b = t2 & 31;
            const int pos = (t2 & ~31) | (((b >> 2) & 3) << 3) | (((b >> 4) & 1) << 2) | (b & 3);
            vo[(size_t)(R >> 11) * HD * TS + (size_t)rcol * TS + pos] = (_Float16)av;
          }
        }
      }
  }
  gridbar(cnt, 1);

  // ===== phase 2: attn. 64 q/block; halves split keys (1024 each), 4 q-waves x 16 q.
  // 32-key chunks, 3-buf DMA (48 KB), vmcnt keep-2. S^T=K Q^T; exp2; l via P*ones; f16 PV.
  {
    const int half = wv >> 2, qw = wv & 3;
    const int batch = blk & 7, qg = blk >> 3;     // XCD swizzle: batch K/V pinned per XCD L2
    const int m0 = batch * TS + qg * 64;
    const short*    kb = ko + (size_t)batch * TS * HD;
    const _Float16* vb = vo + (size_t)batch * HD * TS;

    auto kbuf = [&](int b) { return (short*)   (smem +         half * 12288 + b * 4096); };
    auto vbuf = [&](int b) { return (_Float16*)(smem + 24576 + half * 12288 + b * 4096); };

    auto dmaKV = [&](int t) {                    // chunk t: keys [half*1024 + t*32, +32)
      const int b = t % 3;
      const int c0 = half * 1024 + t * 32;
      {
        const int key = (qw << 3) + (lane >> 3);
        const int s = lane & 7;
        gl2lds(&kb[(size_t)(c0 + key) * HD + (((s + key) & 7) << 3)], kbuf(b) + (qw << 3) * 64);
      }
      {
        const int d = (qw << 4) + (lane >> 2);
        const int s = lane & 3;
        gl2lds(&vb[(size_t)d * TS + c0 + (((s + d) & 3) << 3)], vbuf(b) + (qw << 4) * 32);
      }
    };

    s8v qf[2];
#pragma unroll
    for (int kc = 0; kc < 2; ++kc)
      qf[kc] = *(const s8v*)&qo[(size_t)(m0 + qw * 16 + n) * HD + kc * 32 + quad * 8];

    f4 o[4] = {fz, fz, fz, fz};
    f4 lD = fz;
    h8 ones;
#pragma unroll
    for (int j = 0; j < 8; ++j) ones[j] = (_Float16)1.0f;

    dmaKV(0); dmaKV(1);
    wait_barrier<2>();

    for (int t = 0; t < 32; ++t) {
      if (t < 30) dmaKV(t + 2);
      {
        const short*    ks = kbuf(t % 3);
        const _Float16* vs = vbuf(t % 3);
        s8v kf[2][2];
#pragma unroll
        for (int f = 0; f < 2; ++f)
#pragma unroll
          for (int kc = 0; kc < 2; ++kc) {
            const int key = f * 16 + n;
            kf[f][kc] = *(const s8v*)&ks[key * 64 + (((kc * 4 + quad) - key) & 7) * 8];
          }
        f4 st[2];
#pragma unroll
        for (int f = 0; f < 2; ++f) {
          st[f] = __builtin_amdgcn_mfma_f32_16x16x32_bf16(kf[f][0], qf[0], fz, 0, 0, 0);
          st[f] = __builtin_amdgcn_mfma_f32_16x16x32_bf16(kf[f][1], qf[1], st[f], 0, 0, 0);
        }
        h8 pa;
#pragma unroll
        for (int hf = 0; hf < 2; ++hf)
#pragma unroll
          for (int i = 0; i < 4; ++i)
            pa[hf * 4 + i] = (_Float16)__builtin_amdgcn_exp2f(st[hf][i]);

        lD = __builtin_amdgcn_mfma_f32_16x16x32_f16(pa, ones, lD, 0, 0, 0);
#pragma unroll
        for (int g = 0; g < 4; ++g) {
          const int d = g * 16 + n;
          const h8 vf = *(const h8*)&vs[d * 32 + ((quad - d) & 3) * 8];
          o[g] = __builtin_amdgcn_mfma_f32_16x16x32_f16(pa, vf, o[g], 0, 0, 0);
        }
      }
      if (t < 30)      wait_barrier<2>();   // KV(t+1) landed; KV(t+2) flying
      else if (t < 31) wait_barrier<0>();
    }

    __syncthreads();                         // done with K/V LDS before overlay
    float* o_c = (float*)smem;               // [8 waves][16 q][68]
    float* l_c = (float*)(smem + 34816);     // [8][16]
    if (n == 0)
#pragma unroll
      for (int i = 0; i < 4; ++i) l_c[wv * 16 + quad * 4 + i] = lD[i];
#pragma unroll
    for (int g = 0; g < 4; ++g)
#pragma unroll
      for (int i = 0; i < 4; ++i)
        o_c[(wv * 16 + quad * 4 + i) * 68 + g * 16 + n] = o[g][i];
    __syncthreads();

    // combine halves: 512 thr = 64 q x 8 d-groups of 8
    const int qr = tid >> 3, d8 = (tid & 7) * 8;
    const int qw2 = qr >> 4, wr = qr & 15;
    const float L = l_c[qw2 * 16 + wr] + l_c[(qw2 + 4) * 16 + wr];
    const float inv = 1.0f / L;
    f4 s0 = *(const f4*)&o_c[(qw2 * 16 + wr) * 68 + d8];
    f4 s1 = *(const f4*)&o_c[(qw2 * 16 + wr) * 68 + d8 + 4];
    s0 += *(const f4*)&o_c[((qw2 + 4) * 16 + wr) * 68 + d8];
    s1 += *(const f4*)&o_c[((qw2 + 4) * 16 + wr) * 68 + d8 + 4];
    s0 *= inv; s1 *= inv;
    *(f4*)&out[(size_t)(m0 + qr) * HD + d8]     = s0;
    *(f4*)&out[(size_t)(m0 + qr) * HD + d8 + 4] = s1;
  }
}

extern "C" void kernel_launch(void* const* d_in, const int* in_sizes, int n_in,
                              void* d_out, int out_size, void* d_ws, size_t ws_size,
                              hipStream_t stream) {
  const float* x  = (const float*)d_in[0];
  const float* Wk = (const float*)d_in[1];
  const float* Wq = (const float*)d_in[2];
  const float* Wv = (const float*)d_in[3];
  float* out = (float*)d_out;

  short* qb = (short*)d_ws;                           // [MTOT][64] bf16 (pre-scaled)
  short* kb = qb + (size_t)MTOT * HD;                 // [MTOT][64] bf16
  _Float16* vb = (_Float16*)(kb + (size_t)MTOT * HD); // [NB][64][TS] f16, key-swizzled
  short* wb = (short*)(vb + (size_t)NB * HD * TS);    // [192][1024] bf16 weights
  uint32_t* cnt = (uint32_t*)((char*)d_ws + (64u << 20)); // grid-barrier counters

  hipMemsetAsync(cnt, 0, 64, stream);                 // ws is poisoned 0xAA each replay
  fused_kernel<<<NBLK, 512, 0, stream>>>(x, Wk, Wq, Wv, wb, qb, kb, vb, out, cnt);
}

// Round 9
// 131.451 us; speedup vs baseline: 2.7889x; 2.7889x over previous
//
#include <hip/hip_runtime.h>
#include <cstdint>

#define NB 8
#define TS 2048
#define NE 1024
#define HD 64
#define MTOT (NB*TS)

typedef float     f4  __attribute__((ext_vector_type(4)));
typedef short     s8v __attribute__((ext_vector_type(8)));
typedef short     s4v __attribute__((ext_vector_type(4)));
typedef int       i4v __attribute__((ext_vector_type(4)));
typedef _Float16  h8  __attribute__((ext_vector_type(8)));

__device__ __forceinline__ short f2bf(float f) {  // RNE
  union { float f; uint32_t u; } x; x.f = f;
  return (short)((x.u + 0x7FFFu + ((x.u >> 16) & 1u)) >> 16);
}

// pack two fp32 -> (bf16(lo) | bf16(hi)<<16) via +0x8000 round + v_perm byte select
__device__ __forceinline__ int pack2(float lo, float hi) {
  union { float f; uint32_t u; } a, b; a.f = lo; b.f = hi;
  return (int)__builtin_amdgcn_perm(b.u + 0x8000u, a.u + 0x8000u, 0x07060302u);
}

// async global->LDS DMA, 16B/lane; lptr wave-uniform, lane i -> lptr + i*16
__device__ __forceinline__ void gl2lds(const void* gptr, void* lptr) {
  auto g = (const __attribute__((address_space(1))) uint32_t*)gptr;
  auto l = (__attribute__((address_space(3))) uint32_t*)lptr;
  __builtin_amdgcn_global_load_lds(g, l, 16, 0, 0);
}

// barrier that keeps N newest vmem ops in flight
template <int N>
__device__ __forceinline__ void wait_barrier() {
  asm volatile("s_waitcnt vmcnt(%0) lgkmcnt(0)" :: "n"(N) : "memory");
  __builtin_amdgcn_s_barrier();
}

// ---- kernel 0: W fp32 -> bf16 (q-scale folded). wb [192][1024]: 0-63 q, 64-127 k, 128-191 v
__global__ __launch_bounds__(256) void wconv_kernel(
    const float* __restrict__ Wk, const float* __restrict__ Wq, const float* __restrict__ Wv,
    short* __restrict__ wb)
{
  const int idx = (blockIdx.x * 256 + threadIdx.x) * 4;
  const int p = idx >> 16;
  const int off = idx & 65535;
  const float* W = (p == 0) ? Wq : (p == 1) ? Wk : Wv;
  const float s = (p == 0) ? 0.18033688011112042f : 1.0f; // (1/8)*log2(e)
  const float4 v = *(const float4*)&W[off];
  s4v h; h[0] = f2bf(v.x*s); h[1] = f2bf(v.y*s); h[2] = f2bf(v.z*s); h[3] = f2bf(v.w*s);
  *(s4v*)&wb[idx] = h;
}

// ---- kernel 1: fused qkv projection (r7, unchanged). grid 512 x 256 thr, tile 32x192,
// wave = 16 rows x 96 cols. LDS 80 KB -> 2 blocks/CU. x 4-buf DMA 3-ahead; W 2-buf 1-ahead.
__global__ __launch_bounds__(256) void proj_kernel(
    const float* __restrict__ x, const short* __restrict__ wb,
    short* __restrict__ qo, short* __restrict__ ko, _Float16* __restrict__ vo)
{
  __shared__ float Xs[4][32][64];    // 32 KB
  __shared__ short Ws[2][192][64];   // 48 KB
  const int tid = threadIdx.x;
  const int wv = tid >> 6, lane = tid & 63, n = lane & 15, quad = lane >> 4;
  const int mg = wv & 1, cg = wv >> 1;
  const int r0 = blockIdx.x * 32;
  const int xrow = lane >> 4, xslot = lane & 15;
  const int wrow = lane >> 3, wslot = lane & 7;

  auto dmaX = [&](int c, int buf) {
#pragma unroll
    for (int u = 0; u < 2; ++u) {
      const int R0 = (wv * 2 + u) * 4;
      const int row = R0 + xrow;
      const int gs = (xslot + row) & 15;
      gl2lds(&x[(size_t)(r0 + row) * NE + c * 64 + gs * 4], &Xs[buf][R0][0]);
    }
  };
  auto dmaW = [&](int c, int buf) {
#pragma unroll
    for (int u = 0; u < 6; ++u) {
      const int C0 = (wv * 6 + u) * 8;
      const int col = C0 + wrow;
      const int gs = (wslot + col) & 7;
      gl2lds(&wb[(size_t)col * NE + c * 64 + gs * 8], &Ws[buf][C0][0]);
    }
  };

  const f4 fz = {0.f, 0.f, 0.f, 0.f};
  f4 acc[6] = {fz, fz, fz, fz, fz, fz};

  auto compute = [&](int bw, int bx) {
    s8v a[2];
    const int row = mg * 16 + n;
#pragma unroll
    for (int kc = 0; kc < 2; ++kc) {
      const int u0 = kc * 8 + quad * 2;
      const float* pr = &Xs[bx][row][0];
      const f4 f0 = *(const f4*)(pr + (((u0    ) - row) & 15) * 4);
      const f4 f1 = *(const f4*)(pr + (((u0 + 1) - row) & 15) * 4);
      i4v ai;
      ai[0] = pack2(f0[0], f0[1]); ai[1] = pack2(f0[2], f0[3]);
      ai[2] = pack2(f1[0], f1[1]); ai[3] = pack2(f1[2], f1[3]);
      a[kc] = __builtin_bit_cast(s8v, ai);
    }
#pragma unroll
    for (int nf = 0; nf < 6; ++nf) {
      const int col = cg * 96 + nf * 16 + n;
      const s8v b0 = *(const s8v*)&Ws[bw][col][(((0 + quad) - col) & 7) * 8];
      const s8v b1 = *(const s8v*)&Ws[bw][col][(((4 + quad) - col) & 7) * 8];
      acc[nf] = __builtin_amdgcn_mfma_f32_16x16x32_bf16(a[0], b0, acc[nf], 0, 0, 0);
      acc[nf] = __builtin_amdgcn_mfma_f32_16x16x32_bf16(a[1], b1, acc[nf], 0, 0, 0);
    }
  };

  dmaW(0, 0); dmaX(0, 0); dmaX(1, 1); dmaX(2, 2);
  wait_barrier<4>();

  for (int t = 0; t < 16; ++t) {
    if (t <= 14) dmaW(t + 1, (t + 1) & 1);
    if (t <= 12) dmaX(t + 3, (t + 3) & 3);
    compute(t & 1, t & 3);
    if (t <= 12)      wait_barrier<2>();
    else if (t <= 14) wait_barrier<0>();
  }

#pragma unroll
  for (int nf = 0; nf < 6; ++nf) {
    const int gc = cg * 96 + nf * 16;
    const int p = gc >> 6;
    const int rcol = (gc & 63) + n;
#pragma unroll
    for (int i = 0; i < 4; ++i) {
      const int R = r0 + mg * 16 + quad * 4 + i;
      const float av = acc[nf][i];
      if (p == 0)      qo[(size_t)R * HD + rcol] = f2bf(av);
      else if (p == 1) ko[(size_t)R * HD + rcol] = f2bf(av);
      else {
        // V transposed [b][d][t'] + 32-key-group swizzle so attn PV B-frags are single 16B loads
        const int t2 = R & (TS - 1), b = t2 & 31;
        const int pos = (t2 & ~31) | (((b >> 2) & 3) << 3) | (((b >> 4) & 1) << 2) | (b & 3);
        vo[(size_t)(R >> 11) * HD * TS + (size_t)rcol * TS + pos] = (_Float16)av;
      }
    }
  }
}

// ---- kernel 2: attention. grid 512 x 256 thr (4 waves = 2 key-halves x 2 q-waves x 16 q).
// 32 q/block. Per half: 64-key chunks, 2-buf DMA. LDS exactly 64 KB -> 2 blocks/CU so two
// independent blocks interleave across barrier drains. S^T=K Q^T; exp2; l via P*ones; f16 PV.
__global__ __launch_bounds__(256) void attn_kernel(
    const short* __restrict__ q, const short* __restrict__ k,
    const _Float16* __restrict__ vT, float* __restrict__ out)
{
  __shared__ __align__(16) char smem[65536];   // K[2 half][2 buf][64][64]s | V[...]h
  const int tid = threadIdx.x;
  const int wv = tid >> 6, lane = tid & 63, n = lane & 15, quad = lane >> 4;
  const int half = wv >> 1, qw = wv & 1;
  const int batch = blockIdx.x & 7;            // XCD swizzle: batch K/V pinned per XCD L2
  const int qg = blockIdx.x >> 3;
  const int m0 = batch * TS + qg * 32;
  const short*    kb = k  + (size_t)batch * TS * HD;
  const _Float16* vb = vT + (size_t)batch * HD * TS;
  const f4 fz = {0.f, 0.f, 0.f, 0.f};

  auto kbuf = [&](int b) { return (short*)   (smem +         (half * 2 + b) * 8192); };
  auto vbuf = [&](int b) { return (_Float16*)(smem + 32768 + (half * 2 + b) * 8192); };

  // chunk t: keys [half*1024 + t*64, +64). Both waves of a half cooperate (qw splits rows).
  auto dmaKV = [&](int t) {
    const int b = t & 1;
    const int c0 = half * 1024 + t * 64;
    short*    kd = kbuf(b);
    _Float16* vd = vbuf(b);
#pragma unroll
    for (int u = 0; u < 4; ++u) {
      const int K0 = qw * 32 + u * 8;
      const int key = K0 + (lane >> 3);
      const int s = lane & 7;
      gl2lds(&kb[(size_t)(c0 + key) * HD + (((s + key) & 7) << 3)], kd + K0 * 64);
    }
#pragma unroll
    for (int u = 0; u < 4; ++u) {
      const int D0 = qw * 32 + u * 8;
      const int d = D0 + (lane >> 3);
      const int s = lane & 7;
      gl2lds(&vb[(size_t)d * TS + c0 + (((s + d) & 7) << 3)], vd + D0 * 64);
    }
  };

  s8v qf[2];
#pragma unroll
  for (int kc = 0; kc < 2; ++kc)
    qf[kc] = *(const s8v*)&q[(size_t)(m0 + qw * 16 + n) * HD + kc * 32 + quad * 8];

  f4 o[4] = {fz, fz, fz, fz};
  f4 lD = fz;
  h8 ones;
#pragma unroll
  for (int j = 0; j < 8; ++j) ones[j] = (_Float16)1.0f;

  dmaKV(0);
  wait_barrier<0>();

  for (int t = 0; t < 16; ++t) {
    const int buf = t & 1;
    if (t < 15) dmaKV(t + 1);

    const short*    ks = kbuf(buf);
    const _Float16* vs = vbuf(buf);

    s8v kf[4][2];
#pragma unroll
    for (int f = 0; f < 4; ++f)
#pragma unroll
      for (int kc = 0; kc < 2; ++kc) {
        const int key = f * 16 + n;
        kf[f][kc] = *(const s8v*)&ks[key * 64 + (((kc * 4 + quad) - key) & 7) * 8];
      }

    f4 st[4];
#pragma unroll
    for (int f = 0; f < 4; ++f) {
      st[f] = __builtin_amdgcn_mfma_f32_16x16x32_bf16(kf[f][0], qf[0], fz, 0, 0, 0);
      st[f] = __builtin_amdgcn_mfma_f32_16x16x32_bf16(kf[f][1], qf[1], st[f], 0, 0, 0);
    }

    h8 pa[2];
#pragma unroll
    for (int pr = 0; pr < 2; ++pr)
#pragma unroll
      for (int hf = 0; hf < 2; ++hf)
#pragma unroll
        for (int i = 0; i < 4; ++i)
          pa[pr][hf * 4 + i] = (_Float16)__builtin_amdgcn_exp2f(st[pr * 2 + hf][i]);

#pragma unroll
    for (int pr = 0; pr < 2; ++pr) {
      lD = __builtin_amdgcn_mfma_f32_16x16x32_f16(pa[pr], ones, lD, 0, 0, 0);
#pragma unroll
      for (int g = 0; g < 4; ++g) {
        const int d = g * 16 + n;
        const h8 vf = *(const h8*)&vs[d * 64 + (((pr * 4 + quad) - d) & 7) * 8];
        o[g] = __builtin_amdgcn_mfma_f32_16x16x32_f16(pa[pr], vf, o[g], 0, 0, 0);
      }
    }

    if (t < 15) wait_barrier<0>();   // 2-buf: chunk t+1 must land; block B on this CU overlaps
  }

  __syncthreads();                   // done with K/V LDS before combine overlay

  float* o_c = (float*)smem;         // [4 waves][16 q][68]
  float* l_c = (float*)(smem + 17408);
  if (n == 0)
#pragma unroll
    for (int i = 0; i < 4; ++i) l_c[wv * 16 + quad * 4 + i] = lD[i];
#pragma unroll
  for (int g = 0; g < 4; ++g)
#pragma unroll
    for (int i = 0; i < 4; ++i)
      o_c[(wv * 16 + quad * 4 + i) * 68 + g * 16 + n] = o[g][i];
  __syncthreads();

  // combine halves: 256 thr = 32 q x 8 d-groups of 8. wave(half,qw) -> slot half*2+qw
  const int qr = tid >> 3, d8 = (tid & 7) * 8;
  const int qw2 = qr >> 4, wr = qr & 15;
  const float L = l_c[qw2 * 16 + wr] + l_c[(2 + qw2) * 16 + wr];
  const float inv = 1.0f / L;
  f4 s0 = *(const f4*)&o_c[(qw2 * 16 + wr) * 68 + d8];
  f4 s1 = *(const f4*)&o_c[(qw2 * 16 + wr) * 68 + d8 + 4];
  s0 += *(const f4*)&o_c[((2 + qw2) * 16 + wr) * 68 + d8];
  s1 += *(const f4*)&o_c[((2 + qw2) * 16 + wr) * 68 + d8 + 4];
  s0 *= inv; s1 *= inv;
  *(f4*)&out[(size_t)(m0 + qr) * HD + d8]     = s0;
  *(f4*)&out[(size_t)(m0 + qr) * HD + d8 + 4] = s1;
}

extern "C" void kernel_launch(void* const* d_in, const int* in_sizes, int n_in,
                              void* d_out, int out_size, void* d_ws, size_t ws_size,
                              hipStream_t stream) {
  const float* x  = (const float*)d_in[0];
  const float* Wk = (const float*)d_in[1];
  const float* Wq = (const float*)d_in[2];
  const float* Wv = (const float*)d_in[3];
  float* out = (float*)d_out;

  short* qb = (short*)d_ws;                           // [MTOT][64] bf16 (pre-scaled)
  short* kb = qb + (size_t)MTOT * HD;                 // [MTOT][64] bf16
  _Float16* vb = (_Float16*)(kb + (size_t)MTOT * HD); // [NB][64][TS] f16, key-swizzled
  short* wb = (short*)(vb + (size_t)NB * HD * TS);    // [192][1024] bf16 weights

  wconv_kernel<<<192, 256, 0, stream>>>(Wk, Wq, Wv, wb);
  proj_kernel<<<MTOT / 32, 256, 0, stream>>>(x, wb, qb, kb, vb);
  attn_kernel<<<MTOT / 32, 256, 0, stream>>>(qb, kb, vb, out);
}